// Round 1
// baseline (3407.544 us; speedup 1.0000x reference)
//
#include <hip/hip_runtime.h>

// Residual VQ: x [B,N,D] fp32, codebooks [Q,C,D] fp32
// Outputs (flat fp32 in d_out): qout [B*N*D], indices [B*N*Q] (as float), losses [Q]
constexpr int Bq = 8;
constexpr int Nn = 4096;
constexpr int Dd = 256;
constexpr int Qq = 8;
constexpr int Cc = 1024;
constexpr int Mm = Bq * Nn;      // 32768 tokens
constexpr int TT = 32;           // tokens per block
constexpr int NT = 256;          // threads per block

// ---------------------------------------------------------------------------
// prep: cnorm[q*C+c] = sum_d cb[q][c][d]^2 ; zero loss accumulators
// grid: Q*C/4 blocks of 256 (4 waves, one codeword row per wave)
__global__ void prep_kernel(const float* __restrict__ cbs,
                            float* __restrict__ cnorm,
                            float* __restrict__ loss_acc) {
  const int wave = threadIdx.x >> 6;
  const int lane = threadIdx.x & 63;
  const int row  = blockIdx.x * 4 + wave;            // 0 .. Q*C-1
  const float4* r4 = reinterpret_cast<const float4*>(cbs + (size_t)row * Dd);
  const float4 v = r4[lane];                          // 64 lanes x float4 = 256
  float s = v.x * v.x + v.y * v.y + v.z * v.z + v.w * v.w;
#pragma unroll
  for (int off = 32; off; off >>= 1) s += __shfl_down(s, off);
  if (lane == 0) cnorm[row] = s;
  if (blockIdx.x == 0 && threadIdx.x < Qq) loss_acc[threadIdx.x] = 0.0f;
}

// ---------------------------------------------------------------------------
// one VQ stage, fully fused: distances + argmin + gather + residual/qout/loss
// grid: Mm/TT blocks of NT threads
__global__ __launch_bounds__(NT)
void vq_stage(const float* __restrict__ cb,      // [C][D] this stage
              const float* __restrict__ cnorm,   // [C]   this stage
              const float* __restrict__ rin,     // [M][D] residual in
              float* __restrict__ rout,          // [M][D] residual out
              float* __restrict__ qout,          // [M][D] accumulated quantized
              float* __restrict__ idx_out,       // [M][Q] indices as float
              float* __restrict__ loss_acc,      // [Q] loss sums
              int q) {
  __shared__ float4 rs[TT][Dd / 4];               // 32 KB residual tile
  __shared__ float red_v[4][TT];
  __shared__ int   red_i[4][TT];
  __shared__ int   win[TT];

  const int tid  = threadIdx.x;
  const int tok0 = blockIdx.x * TT;

  // stage residual tile: TT*D floats = 2048 float4; 8 per thread, coalesced
  {
    const float4* src = reinterpret_cast<const float4*>(rin + (size_t)tok0 * Dd);
    float4* dst = &rs[0][0];
#pragma unroll
    for (int k = 0; k < (TT * Dd / 4) / NT; ++k) dst[tid + k * NT] = src[tid + k * NT];
  }
  __syncthreads();

  float minv[TT];
  int   mini[TT];
#pragma unroll
  for (int m = 0; m < TT; ++m) { minv[m] = 3.4e38f; mini[m] = 0; }

  // each thread owns codewords {p*512+tid, p*512+tid+256} for p=0,1 (ascending
  // order per thread -> strict-less keeps lowest index on ties)
#pragma unroll 1
  for (int pass = 0; pass < 2; ++pass) {
    const int c0 = pass * 512 + tid;
    const int c1 = c0 + 256;
    const float4* cw0 = reinterpret_cast<const float4*>(cb + (size_t)c0 * Dd);
    const float4* cw1 = reinterpret_cast<const float4*>(cb + (size_t)c1 * Dd);
    float acc0[TT], acc1[TT];
#pragma unroll
    for (int m = 0; m < TT; ++m) { acc0[m] = 0.0f; acc1[m] = 0.0f; }
#pragma unroll 1
    for (int d4 = 0; d4 < Dd / 4; ++d4) {
      const float4 a = cw0[d4];
      const float4 b = cw1[d4];
#pragma unroll
      for (int m = 0; m < TT; ++m) {
        const float4 r = rs[m][d4];                       // LDS broadcast
        acc0[m] += r.x * a.x + r.y * a.y + r.z * a.z + r.w * a.w;
        acc1[m] += r.x * b.x + r.y * b.y + r.z * b.z + r.w * b.w;
      }
    }
    const float cn0 = cnorm[c0];
    const float cn1 = cnorm[c1];
#pragma unroll
    for (int m = 0; m < TT; ++m) {
      const float s0 = cn0 - 2.0f * acc0[m];
      const float s1 = cn1 - 2.0f * acc1[m];
      if (s0 < minv[m]) { minv[m] = s0; mini[m] = c0; }
      if (s1 < minv[m]) { minv[m] = s1; mini[m] = c1; }
    }
  }

  // wave argmin reduce (value, then lowest index on exact ties)
#pragma unroll
  for (int m = 0; m < TT; ++m) {
    float v = minv[m];
    int   i = mini[m];
#pragma unroll
    for (int s = 32; s; s >>= 1) {
      const float ov = __shfl_xor(v, s);
      const int   oi = __shfl_xor(i, s);
      if (ov < v || (ov == v && oi < i)) { v = ov; i = oi; }
    }
    minv[m] = v;
    mini[m] = i;
  }
  const int lane = tid & 63;
  const int wv   = tid >> 6;
  if (lane == 0) {
#pragma unroll
    for (int m = 0; m < TT; ++m) { red_v[wv][m] = minv[m]; red_i[wv][m] = mini[m]; }
  }
  __syncthreads();
  if (tid < TT) {
    float v = red_v[0][tid];
    int   i = red_i[0][tid];
#pragma unroll
    for (int w = 1; w < 4; ++w) {
      const float ov = red_v[w][tid];
      const int   oi = red_i[w][tid];
      if (ov < v || (ov == v && oi < i)) { v = ov; i = oi; }
    }
    win[tid] = i;
    idx_out[(size_t)(tok0 + tid) * Qq + q] = (float)i;   // indices as float
  }
  __syncthreads();

  // epilogue: gather winner codeword, loss, residual & qout update.
  // Replicates reference fp32 elementwise sequence:
  //   e = q - r; q_st = r + e; r_new = r - q_st; qout += q_st; loss += e^2
  float lsum = 0.0f;
  {
    const float4* cb4   = reinterpret_cast<const float4*>(cb);
    float4* routp = reinterpret_cast<float4*>(rout + (size_t)tok0 * Dd);
    float4* qoutp = reinterpret_cast<float4*>(qout + (size_t)tok0 * Dd);
#pragma unroll
    for (int k = 0; k < (TT * Dd / 4) / NT; ++k) {
      const int j  = tid + k * NT;
      const int m  = j >> 6;        // wave-uniform token
      const int d4 = j & 63;
      const int widx = win[m];
      const float4 cv = cb4[(size_t)widx * (Dd / 4) + d4];
      const float4 rv = rs[m][d4];
      const float ex = cv.x - rv.x, ey = cv.y - rv.y, ez = cv.z - rv.z, ew = cv.w - rv.w;
      const float qsx = rv.x + ex, qsy = rv.y + ey, qsz = rv.z + ez, qsw = rv.w + ew;
      lsum += ex * ex + ey * ey + ez * ez + ew * ew;
      routp[j] = make_float4(rv.x - qsx, rv.y - qsy, rv.z - qsz, rv.w - qsw);
      float4 qo;
      if (q == 0) {
        qo = make_float4(qsx, qsy, qsz, qsw);            // overwrite (no stale state)
      } else {
        const float4 old = qoutp[j];
        qo = make_float4(old.x + qsx, old.y + qsy, old.z + qsz, old.w + qsw);
      }
      qoutp[j] = qo;
    }
  }
#pragma unroll
  for (int s = 32; s; s >>= 1) lsum += __shfl_xor(lsum, s);
  if (lane == 0) atomicAdd(&loss_acc[q], lsum);
}

// ---------------------------------------------------------------------------
__global__ void finalize_losses(const float* __restrict__ loss_acc,
                                float* __restrict__ loss_out) {
  if (threadIdx.x < Qq) loss_out[threadIdx.x] = loss_acc[threadIdx.x] * (1.0f / (float)(Mm * Dd));
}

extern "C" void kernel_launch(void* const* d_in, const int* in_sizes, int n_in,
                              void* d_out, int out_size, void* d_ws, size_t ws_size,
                              hipStream_t stream) {
  const float* x   = (const float*)d_in[0];   // [B,N,D]
  const float* cbs = (const float*)d_in[1];   // [Q,C,D]
  float* out      = (float*)d_out;
  float* qout     = out;                               // M*D
  float* idx_out  = out + (size_t)Mm * Dd;             // M*Q
  float* loss_out = idx_out + (size_t)Mm * Qq;         // Q

  float* residual = (float*)d_ws;                      // M*D floats = 32 MB
  float* loss_acc = residual + (size_t)Mm * Dd;        // Q floats (pad 64)
  float* cnorm    = loss_acc + 64;                     // Q*C floats

  prep_kernel<<<(Qq * Cc) / 4, NT, 0, stream>>>(cbs, cnorm, loss_acc);

  for (int q = 0; q < Qq; ++q) {
    const float* rin = (q == 0) ? x : residual;
    vq_stage<<<Mm / TT, NT, 0, stream>>>(cbs + (size_t)q * Cc * Dd,
                                         cnorm + (size_t)q * Cc,
                                         rin, residual,
                                         qout, idx_out, loss_acc, q);
  }

  finalize_losses<<<1, 64, 0, stream>>>(loss_acc, loss_out);
}